// Round 12
// baseline (130.483 us; speedup 1.0000x reference)
//
#include <hip/hip_runtime.h>
#include <hip/hip_bf16.h>

#define BATCH 4
#define NPTS 4096
#define KNBR 16
#define D 64
#define NQ (BATCH * NPTS)
#define QPW 2
#define PT_QPW 4

using short8 = __attribute__((ext_vector_type(8))) short;
using short4v = __attribute__((ext_vector_type(4))) short;
using f32x4 = __attribute__((ext_vector_type(4))) float;

__device__ __forceinline__ float rl(float v, int i) {
  return __int_as_float(__builtin_amdgcn_readlane(__float_as_int(v), i));
}
__device__ __forceinline__ short f2bf(float x) {
  __hip_bfloat16 h = __float2bfloat16(x);
  return *reinterpret_cast<short*>(&h);
}
__device__ __forceinline__ float bf2f(short s) {
  union { unsigned u; float f; } v;
  v.u = ((unsigned)(unsigned short)s) << 16;
  return v.f;
}
#define MFMA16(a, b, c) __builtin_amdgcn_mfma_f32_16x16x32_bf16(a, b, c, 0, 0, 0)

#define INF_KEY 0x7F800000FFFFFFFFull

// 64-lane bitonic full sort (ascending by lane) of u64 keys.
__device__ __forceinline__ unsigned long long bitonic64(unsigned long long v, int lane) {
#pragma unroll
  for (int k = 2; k <= 64; k <<= 1) {
#pragma unroll
    for (int j = k >> 1; j > 0; j >>= 1) {
      unsigned long long o = __shfl_xor(v, j);
      const bool up = (lane & k) == 0;
      const bool lower = (lane & j) == 0;
      unsigned long long mn = v < o ? v : o;
      unsigned long long mx = v < o ? o : v;
      v = (up == lower) ? mn : mx;
    }
  }
  return v;
}

// ---------------------------------------------------------------------------
// Kernel 1: exact KNN, u64 keys (u32 variant faults — u64 is keep-forever).
// Full 48KB coord set staged in LDS ONCE per block (pure float4 copy, one
// barrier); both phases scan LDS. Interleaved layout: read cs[3j+c] -> bank
// (3*lane+c)%32, bijection x2 -> conflict-free. Same slice partition
// (j = s*64+lane) and __f*_rn arithmetic as rounds 4..11 -> identical keys.
// LDS 52.3KB -> 3 blocks/CU (12 waves/CU).
// ---------------------------------------------------------------------------
__global__ __launch_bounds__(256, 3) void knn_kernel(const float* __restrict__ coords,
                                                     int* __restrict__ knn) {
  __shared__ float cs[NPTS * 3];                   // 48KB, xyz interleaved
  __shared__ unsigned long long buf[4][QPW][64];   // per-wave filter buffers
  __shared__ int cnt[4][QPW];
  const int t = threadIdx.x;
  const int w = t >> 6, lane = t & 63;
  const int qbase = blockIdx.x * (4 * QPW) + w * QPW;
  const int b = qbase >> 12;
  const float* cb = coords + (size_t)b * NPTS * 3;

  // ---- stage full batch coords once: pure float4 copy, no index math ----
  {
    const float4* s4 = (const float4*)cb;
    float4* d4 = (float4*)cs;
#pragma unroll
    for (int i = 0; i < 12; ++i) d4[t + i * 256] = s4[t + i * 256];
  }

  float qx[QPW], qy[QPW], qz[QPW];
  unsigned long long m[QPW];
#pragma unroll
  for (int q = 0; q < QPW; ++q) {
    const int qi = (qbase + q) & (NPTS - 1);
    qx[q] = cb[(size_t)qi * 3];
    qy[q] = cb[(size_t)qi * 3 + 1];
    qz[q] = cb[(size_t)qi * 3 + 2];
    m[q] = INF_KEY;
  }
  __syncthreads();  // cs staged

  // ---- phase 1: per-lane slice minima over the 64-candidate slices ----
#pragma unroll 4
  for (int s = 0; s < 64; ++s) {
    const int j = s * 64 + lane;
    const float px = cs[3 * j], py = cs[3 * j + 1], pz = cs[3 * j + 2];
#pragma unroll
    for (int q = 0; q < QPW; ++q) {
      float dx = __fsub_rn(qx[q], px);
      float dy = __fsub_rn(qy[q], py);
      float dz = __fsub_rn(qz[q], pz);
      float d = __fadd_rn(__fadd_rn(__fmul_rn(dx, dx), __fmul_rn(dy, dy)), __fmul_rn(dz, dz));
      unsigned long long key = ((unsigned long long)__float_as_uint(d) << 32) | (unsigned)j;
      m[q] = key < m[q] ? key : m[q];
    }
  }
  // ---- thresholds: 16th-smallest slice-min key per query (64 distinct keys
  //      from disjoint slices -> count(key <= K16) >= 16 is guaranteed) ----
  unsigned long long K16[QPW];
#pragma unroll
  for (int q = 0; q < QPW; ++q) K16[q] = __shfl(bitonic64(m[q], lane), 15);
  if (lane < QPW) cnt[w][lane] = 0;

  // ---- phase 2: filter-append (same-wave LDS ops are in-order) ----
#pragma unroll 4
  for (int s = 0; s < 64; ++s) {
    const int j = s * 64 + lane;
    const float px = cs[3 * j], py = cs[3 * j + 1], pz = cs[3 * j + 2];
#pragma unroll
    for (int q = 0; q < QPW; ++q) {
      float dx = __fsub_rn(qx[q], px);
      float dy = __fsub_rn(qy[q], py);
      float dz = __fsub_rn(qz[q], pz);
      float d = __fadd_rn(__fadd_rn(__fmul_rn(dx, dx), __fmul_rn(dy, dy)), __fmul_rn(dz, dz));
      unsigned long long key = ((unsigned long long)__float_as_uint(d) << 32) | (unsigned)j;
      if (key <= K16[q]) {
        int slot = atomicAdd(&cnt[w][q], 1);
        if (slot < 64) buf[w][q][slot] = key;
      }
    }
  }
  // ---- phase 3: exact sort of each filtered set ----
#pragma unroll
  for (int q = 0; q < QPW; ++q) {
    const int n = cnt[w][q];
    unsigned long long v = (lane < n) ? buf[w][q][lane] : INF_KEY;
    v = bitonic64(v, lane);
    if (lane < 16) knn[(size_t)(qbase + q) * 16 + lane] = (int)(v & 0xFFFFFFFFu);
  }
}

// ---------------------------------------------------------------------------
// Kernel 2: x = feat@w1+b1; q=x@wq; k=x@wk; v=x@wv (wave-per-row, readlane).
// ---------------------------------------------------------------------------
#define FT_RPT 8
__global__ __launch_bounds__(256) void ft_kernel(const float* __restrict__ feat,
    const float* __restrict__ w1, const float* __restrict__ b1,
    const float* __restrict__ wq, const float* __restrict__ wk, const float* __restrict__ wv,
    float* __restrict__ qo, float* __restrict__ ko, float* __restrict__ vo) {
  __shared__ float W[4][D * D];
  const int t = threadIdx.x;
  {
    const float4* s0 = (const float4*)w1;
    const float4* s1 = (const float4*)wq;
    const float4* s2 = (const float4*)wk;
    const float4* s3 = (const float4*)wv;
    for (int c = t; c < D * D / 4; c += 256) {
      ((float4*)W[0])[c] = s0[c]; ((float4*)W[1])[c] = s1[c];
      ((float4*)W[2])[c] = s2[c]; ((float4*)W[3])[c] = s3[c];
    }
  }
  __syncthreads();
  const int f = t & 63, w = t >> 6;
  const float b1f = b1[f];
  const int gw = blockIdx.x * 4 + w;
  for (int r = 0; r < FT_RPT; ++r) {
    const int row = gw * FT_RPT + r;
    const float fv = feat[(size_t)row * D + f];
    float x = b1f;
#pragma unroll
    for (int i = 0; i < D; ++i) x = fmaf(rl(fv, i), W[0][i * D + f], x);
    float q = 0.f, kk = 0.f, vv = 0.f;
#pragma unroll
    for (int i = 0; i < D; ++i) {
      float xi = rl(x, i);
      q  = fmaf(xi, W[1][i * D + f], q);
      kk = fmaf(xi, W[2][i * D + f], kk);
      vv = fmaf(xi, W[3][i * D + f], vv);
    }
    qo[(size_t)row * D + f] = q;
    ko[(size_t)row * D + f] = kk;
    vo[(size_t)row * D + f] = vv;
  }
}

// ---------------------------------------------------------------------------
// Kernel 3: MFMA point-transformer core (round-11 verbatim).
// ---------------------------------------------------------------------------
__global__ __launch_bounds__(256, 4) void pt_kernel(const float* __restrict__ coords,
    const float* __restrict__ feat,
    const float* __restrict__ qws, const float* __restrict__ kws, const float* __restrict__ vws,
    const int* __restrict__ knn,
    const float* __restrict__ wp1, const float* __restrict__ bp1,
    const float* __restrict__ wp2, const float* __restrict__ bp2,
    const float* __restrict__ wm1, const float* __restrict__ bm1,
    const float* __restrict__ wm2, const float* __restrict__ bm2,
    const float* __restrict__ w2g, const float* __restrict__ b2,
    float* __restrict__ out, float* __restrict__ attn_g) {
  __shared__ short WBp[512 * 8], WBm1[512 * 8], WBm2[512 * 8];  // frag-packed weights
  __shared__ float wp1t[D * 4];       // (wp1_x, wp1_y, wp1_z, bp1) per channel
  __shared__ float biases[4 * D];     // bp2, bm1, bm2, b2
  __shared__ int knnq[4][PT_QPW][16];
  __shared__ short xch[4][16][72];    // per-wave bf16 exchange; 144B rows (16B-aligned)

  const int t = threadIdx.x;
  // ---- weight prep (frag order: dst[((tt*2+ks)*64 + lane)*8 + j] = W[k][n]) ----
  for (int s = t; s < 512 * 3; s += 256) {
    const int m = s >> 9, rem = s & 511;
    const int tk = rem >> 6, l = rem & 63;
    const int tt = tk >> 1, ks = tk & 1;
    const float* src = (m == 0) ? wp2 : ((m == 1) ? wm1 : wm2);
    short* dst = (m == 0) ? WBp : ((m == 1) ? WBm1 : WBm2);
#pragma unroll
    for (int j = 0; j < 8; ++j) {
      const int k = ((l >> 4) << 3) + j + (ks << 5);
      const int n = (l & 15) + (tt << 4);
      dst[rem * 8 + j] = f2bf(src[k * D + n]);
    }
  }
  if (t < 64) {
    wp1t[t * 4 + 0] = wp1[t];
    wp1t[t * 4 + 1] = wp1[D + t];
    wp1t[t * 4 + 2] = wp1[2 * D + t];
    wp1t[t * 4 + 3] = bp1[t];
    biases[t] = bp2[t]; biases[64 + t] = bm1[t];
    biases[128 + t] = bm2[t]; biases[192 + t] = b2[t];
  }
  const int w = t >> 6, lane = t & 63;
  const int qbase0 = blockIdx.x * (4 * PT_QPW) + w * PT_QPW;
  {
    const int q = lane >> 4, k = lane & 15;
    const int qi = qbase0 + q;
    const int bbase = (qi >> 12) << 12;
    knnq[w][q][k] = bbase + knn[(size_t)qi * 16 + k];
  }
  __syncthreads();

  const int l15 = lane & 15, g = lane >> 4;
  float ovq[PT_QPW];

  for (int q = 0; q < PT_QPW; ++q) {
    const int qi = qbase0 + q;
    const int gjA = knnq[w][q][l15];
    // ---- h1 = relu(rel @ wp1 + bp1), built directly in A-frag layout ----
    const float qx = coords[(size_t)qi * 3], qy = coords[(size_t)qi * 3 + 1], qz = coords[(size_t)qi * 3 + 2];
    const float rx = qx - coords[(size_t)gjA * 3];
    const float ry = qy - coords[(size_t)gjA * 3 + 1];
    const float rz = qz - coords[(size_t)gjA * 3 + 2];
    short8 ha[2];
#pragma unroll
    for (int ks = 0; ks < 2; ++ks) {
#pragma unroll
      for (int j = 0; j < 8; ++j) {
        const int c = g * 8 + j + ks * 32;
        const float4 wv = *(const float4*)&wp1t[c * 4];
        float h = fmaf(rx, wv.x, fmaf(ry, wv.y, fmaf(rz, wv.z, wv.w)));
        ha[ks][j] = f2bf(fmaxf(h, 0.f));
      }
    }
    // ---- pos_enc = h1 @ wp2 + bp2 (f32 in pe_d regs; bf16 copy to xch) ----
    f32x4 pe_d[4];
#pragma unroll
    for (int tt = 0; tt < 4; ++tt) {
      f32x4 acc = {0.f, 0.f, 0.f, 0.f};
      acc = MFMA16(ha[0], *(const short8*)&WBp[((tt * 2 + 0) * 64 + lane) * 8], acc);
      acc = MFMA16(ha[1], *(const short8*)&WBp[((tt * 2 + 1) * 64 + lane) * 8], acc);
      const float bb = biases[l15 + tt * 16];
#pragma unroll
      for (int r = 0; r < 4; ++r) {
        pe_d[tt][r] = acc[r] + bb;
        xch[w][4 * g + r][l15 + 16 * tt] = f2bf(pe_d[tt][r]);
      }
    }
    __syncthreads();  // xch(pe) visible before cross-lane A-frag build
    // ---- a = q - k_g + pos_enc, in A-frag layout ----
    short8 aa[2];
#pragma unroll
    for (int ks = 0; ks < 2; ++ks) {
      const int c0 = g * 8 + ks * 32;
      const float4 q0 = *(const float4*)&qws[(size_t)qi * D + c0];
      const float4 q1 = *(const float4*)&qws[(size_t)qi * D + c0 + 4];
      const float4 k0 = *(const float4*)&kws[(size_t)gjA * D + c0];
      const float4 k1 = *(const float4*)&kws[(size_t)gjA * D + c0 + 4];
      const short8 pv = *(const short8*)&xch[w][l15][c0];
      aa[ks][0] = f2bf(q0.x - k0.x + bf2f(pv[0]));
      aa[ks][1] = f2bf(q0.y - k0.y + bf2f(pv[1]));
      aa[ks][2] = f2bf(q0.z - k0.z + bf2f(pv[2]));
      aa[ks][3] = f2bf(q0.w - k0.w + bf2f(pv[3]));
      aa[ks][4] = f2bf(q1.x - k1.x + bf2f(pv[4]));
      aa[ks][5] = f2bf(q1.y - k1.y + bf2f(pv[5]));
      aa[ks][6] = f2bf(q1.z - k1.z + bf2f(pv[6]));
      aa[ks][7] = f2bf(q1.w - k1.w + bf2f(pv[7]));
    }
    // ---- a2 = relu(a @ wm1 + bm1) -> bf16 -> xch (reuse; pe dead now) ----
#pragma unroll
    for (int tt = 0; tt < 4; ++tt) {
      f32x4 acc = {0.f, 0.f, 0.f, 0.f};
      acc = MFMA16(aa[0], *(const short8*)&WBm1[((tt * 2 + 0) * 64 + lane) * 8], acc);
      acc = MFMA16(aa[1], *(const short8*)&WBm1[((tt * 2 + 1) * 64 + lane) * 8], acc);
      const float bb = biases[64 + l15 + tt * 16];
#pragma unroll
      for (int r = 0; r < 4; ++r)
        xch[w][4 * g + r][l15 + 16 * tt] = f2bf(fmaxf(acc[r] + bb, 0.f));
    }
    __syncthreads();  // xch(a2) visible before cross-lane reads
    // ---- a3 = a2 @ wm2 + bm2 ----
    const short8 a20 = *(const short8*)&xch[w][l15][g * 8];
    const short8 a21 = *(const short8*)&xch[w][l15][g * 8 + 32];
    f32x4 s3[4];
#pragma unroll
    for (int tt = 0; tt < 4; ++tt) {
      f32x4 acc = {0.f, 0.f, 0.f, 0.f};
      acc = MFMA16(a20, *(const short8*)&WBm2[((tt * 2 + 0) * 64 + lane) * 8], acc);
      acc = MFMA16(a21, *(const short8*)&WBm2[((tt * 2 + 1) * 64 + lane) * 8], acc);
      const float bb = biases[128 + l15 + tt * 16];
#pragma unroll
      for (int r = 0; r < 4; ++r) s3[tt][r] = acc[r] + bb;
    }
    // ---- softmax over the 16 neighbors (rows), per channel (col) ----
    float att[4][4];
#pragma unroll
    for (int tt = 0; tt < 4; ++tt) {
      float v0 = s3[tt][0] * 0.125f, v1 = s3[tt][1] * 0.125f;
      float v2 = s3[tt][2] * 0.125f, v3 = s3[tt][3] * 0.125f;
      float mx = fmaxf(fmaxf(v0, v1), fmaxf(v2, v3));
      mx = fmaxf(mx, __shfl_xor(mx, 16));
      mx = fmaxf(mx, __shfl_xor(mx, 32));
      float e0 = __expf(v0 - mx), e1 = __expf(v1 - mx), e2 = __expf(v2 - mx), e3 = __expf(v3 - mx);
      float sm = (e0 + e1) + (e2 + e3);
      sm += __shfl_xor(sm, 16);
      sm += __shfl_xor(sm, 32);
      const float inv = 1.0f / sm;
      att[tt][0] = e0 * inv; att[tt][1] = e1 * inv;
      att[tt][2] = e2 * inv; att[tt][3] = e3 * inv;
    }
    // ---- attn store: bf16 bounce via xch -> 4x 1KB coalesced stores ----
    __syncthreads();  // xch(a2) reads complete in all lanes
#pragma unroll
    for (int tt = 0; tt < 4; ++tt)
#pragma unroll
      for (int r = 0; r < 4; ++r)
        xch[w][4 * g + r][l15 + 16 * tt] = f2bf(att[tt][r]);
    __syncthreads();  // xch(attn) visible
    {
      float* aq = attn_g + (size_t)qi * KNBR * D;
#pragma unroll
      for (int k = 0; k < 4; ++k) {
        const short4v sv = *(const short4v*)&xch[w][g + 4 * k][4 * l15];
        float4 fv;
        fv.x = bf2f(sv.x); fv.y = bf2f(sv.y); fv.z = bf2f(sv.z); fv.w = bf2f(sv.w);
        *(float4*)(aq + lane * 4 + k * 256) = fv;
      }
    }
    // ---- out_vec = sum_k attn * (v_g + pos_enc); pe is register-local ----
    float ovp[4] = {0.f, 0.f, 0.f, 0.f};
#pragma unroll
    for (int r = 0; r < 4; ++r) {
      const int gjr = knnq[w][q][4 * g + r];
#pragma unroll
      for (int tt = 0; tt < 4; ++tt) {
        const float vv = vws[(size_t)gjr * D + l15 + 16 * tt];
        ovp[tt] = fmaf(att[tt][r], vv + pe_d[tt][r], ovp[tt]);
      }
    }
#pragma unroll
    for (int tt = 0; tt < 4; ++tt) {
      ovp[tt] += __shfl_xor(ovp[tt], 16);
      ovp[tt] += __shfl_xor(ovp[tt], 32);
    }
    ovq[q] = (g == 0) ? ovp[0] : ((g == 1) ? ovp[1] : ((g == 2) ? ovp[2] : ovp[3]));
  }

  // ---- out = ov @ w2 + b2 + feat, 4 queries interleaved (ILP), w2 from L1 ----
  float o2[PT_QPW];
#pragma unroll
  for (int q = 0; q < PT_QPW; ++q) o2[q] = biases[192 + lane];
#pragma unroll 8
  for (int i = 0; i < D; ++i) {
    const float wv = w2g[i * D + lane];
#pragma unroll
    for (int q = 0; q < PT_QPW; ++q) o2[q] = fmaf(rl(ovq[q], i), wv, o2[q]);
  }
#pragma unroll
  for (int q = 0; q < PT_QPW; ++q) {
    const int qi = qbase0 + q;
    out[(size_t)qi * D + lane] = o2[q] + feat[(size_t)qi * D + lane];
  }
}

// ---------------------------------------------------------------------------
extern "C" void kernel_launch(void* const* d_in, const int* in_sizes, int n_in,
                              void* d_out, int out_size, void* d_ws, size_t ws_size,
                              hipStream_t stream) {
  const float* coords = (const float*)d_in[0];
  const float* feat   = (const float*)d_in[1];
  const float* w1  = (const float*)d_in[2];
  const float* b1  = (const float*)d_in[3];
  const float* w2  = (const float*)d_in[4];
  const float* b2  = (const float*)d_in[5];
  const float* wq  = (const float*)d_in[6];
  const float* wk  = (const float*)d_in[7];
  const float* wv  = (const float*)d_in[8];
  const float* wm1 = (const float*)d_in[9];
  const float* bm1 = (const float*)d_in[10];
  const float* wm2 = (const float*)d_in[11];
  const float* bm2 = (const float*)d_in[12];
  const float* wp1 = (const float*)d_in[13];
  const float* bp1 = (const float*)d_in[14];
  const float* wp2 = (const float*)d_in[15];
  const float* bp2 = (const float*)d_in[16];

  // ws layout (disjoint): knn@0 (1MB), qws@1MB, kws@5MB, vws@9MB..13MB.
  int* knn = (int*)d_ws;
  float* qws = (float*)((char*)d_ws + (size_t)1 * (1 << 20));
  float* kws = (float*)((char*)d_ws + (size_t)5 * (1 << 20));
  float* vws = (float*)((char*)d_ws + (size_t)9 * (1 << 20));
  float* out  = (float*)d_out;
  float* attn = out + (size_t)NQ * D;

  hipLaunchKernelGGL(knn_kernel, dim3(NQ / (4 * QPW)), dim3(256), 0, stream,
                     coords, knn);
  hipLaunchKernelGGL(ft_kernel, dim3(NQ / (4 * FT_RPT)), dim3(256), 0, stream,
                     feat, w1, b1, wq, wk, wv, qws, kws, vws);
  hipLaunchKernelGGL(pt_kernel, dim3(NQ / (4 * PT_QPW)), dim3(256), 0, stream,
                     coords, feat, qws, kws, vws, knn,
                     wp1, bp1, wp2, bp2, wm1, bm1, wm2, bm2, w2, b2, out, attn);
}

// Round 13
// 110.685 us; speedup vs baseline: 1.1789x; 1.1789x over previous
//
#include <hip/hip_runtime.h>
#include <hip/hip_bf16.h>

#define BATCH 4
#define NPTS 4096
#define KNBR 16
#define D 64
#define NQ (BATCH * NPTS)
#define QPW 2
#define PT_QPW 4

using short8 = __attribute__((ext_vector_type(8))) short;
using short4v = __attribute__((ext_vector_type(4))) short;
using f32x4 = __attribute__((ext_vector_type(4))) float;

__device__ __forceinline__ float rl(float v, int i) {
  return __int_as_float(__builtin_amdgcn_readlane(__float_as_int(v), i));
}
__device__ __forceinline__ short f2bf(float x) {
  __hip_bfloat16 h = __float2bfloat16(x);
  return *reinterpret_cast<short*>(&h);
}
__device__ __forceinline__ float bf2f(short s) {
  union { unsigned u; float f; } v;
  v.u = ((unsigned)(unsigned short)s) << 16;
  return v.f;
}
#define MFMA16(a, b, c) __builtin_amdgcn_mfma_f32_16x16x32_bf16(a, b, c, 0, 0, 0)

#define INF_KEY 0x7F800000FFFFFFFFull

// 64-lane bitonic full sort (ascending by lane) of u64 keys.
__device__ __forceinline__ unsigned long long bitonic64(unsigned long long v, int lane) {
#pragma unroll
  for (int k = 2; k <= 64; k <<= 1) {
#pragma unroll
    for (int j = k >> 1; j > 0; j >>= 1) {
      unsigned long long o = __shfl_xor(v, j);
      const bool up = (lane & k) == 0;
      const bool lower = (lane & j) == 0;
      unsigned long long mn = v < o ? v : o;
      unsigned long long mx = v < o ? o : v;
      v = (up == lower) ? mn : mx;
    }
  }
  return v;
}

// ---------------------------------------------------------------------------
// Kernel 1 (round-11 verbatim — best measured config): exact KNN, u64 keys,
// QPW=2 queries/wave, candidates streamed from global (L2-resident).
// ---------------------------------------------------------------------------
__global__ __launch_bounds__(256, 8) void knn_kernel(const float* __restrict__ coords,
                                                     int* __restrict__ knn) {
  __shared__ unsigned long long buf[4][QPW][64];   // per-wave filter buffers
  __shared__ int cnt[4][QPW];
  const int t = threadIdx.x;
  const int w = t >> 6, lane = t & 63;
  const int qbase = blockIdx.x * (4 * QPW) + w * QPW;
  const int b = qbase >> 12;
  const float* cb = coords + (size_t)b * NPTS * 3;

  float qx[QPW], qy[QPW], qz[QPW];
  unsigned long long m[QPW];
#pragma unroll
  for (int q = 0; q < QPW; ++q) {
    const int qi = (qbase + q) & (NPTS - 1);
    qx[q] = cb[(size_t)qi * 3];
    qy[q] = cb[(size_t)qi * 3 + 1];
    qz[q] = cb[(size_t)qi * 3 + 2];
    m[q] = INF_KEY;
  }

  // ---- phase 1: per-lane slice minima over the 64-candidate slices ----
#pragma unroll 4
  for (int s = 0; s < 64; ++s) {
    const int j = s * 64 + lane;
    const float px = cb[3 * j], py = cb[3 * j + 1], pz = cb[3 * j + 2];
#pragma unroll
    for (int q = 0; q < QPW; ++q) {
      float dx = __fsub_rn(qx[q], px);
      float dy = __fsub_rn(qy[q], py);
      float dz = __fsub_rn(qz[q], pz);
      float d = __fadd_rn(__fadd_rn(__fmul_rn(dx, dx), __fmul_rn(dy, dy)), __fmul_rn(dz, dz));
      unsigned long long key = ((unsigned long long)__float_as_uint(d) << 32) | (unsigned)j;
      m[q] = key < m[q] ? key : m[q];
    }
  }
  // ---- thresholds: 16th-smallest slice-min key per query ----
  unsigned long long K16[QPW];
#pragma unroll
  for (int q = 0; q < QPW; ++q) K16[q] = __shfl(bitonic64(m[q], lane), 15);
  if (lane < QPW) cnt[w][lane] = 0;

  // ---- phase 2: filter-append (same-wave LDS ops are in-order) ----
#pragma unroll 4
  for (int s = 0; s < 64; ++s) {
    const int j = s * 64 + lane;
    const float px = cb[3 * j], py = cb[3 * j + 1], pz = cb[3 * j + 2];
#pragma unroll
    for (int q = 0; q < QPW; ++q) {
      float dx = __fsub_rn(qx[q], px);
      float dy = __fsub_rn(qy[q], py);
      float dz = __fsub_rn(qz[q], pz);
      float d = __fadd_rn(__fadd_rn(__fmul_rn(dx, dx), __fmul_rn(dy, dy)), __fmul_rn(dz, dz));
      unsigned long long key = ((unsigned long long)__float_as_uint(d) << 32) | (unsigned)j;
      if (key <= K16[q]) {
        int slot = atomicAdd(&cnt[w][q], 1);
        if (slot < 64) buf[w][q][slot] = key;
      }
    }
  }
  // ---- phase 3: exact sort of each filtered set ----
#pragma unroll
  for (int q = 0; q < QPW; ++q) {
    const int n = cnt[w][q];
    unsigned long long v = (lane < n) ? buf[w][q][lane] : INF_KEY;
    v = bitonic64(v, lane);
    if (lane < 16) knn[(size_t)(qbase + q) * 16 + lane] = (int)(v & 0xFFFFFFFFu);
  }
}

// ---------------------------------------------------------------------------
// Kernel 2 (NEW): MFMA ft. X = feat@w1+b1; Q=X@wq; K=X@wk; V=X@wv.
// Reuses pt's verified fragment layouts: B-frags packed in LDS, A-frag
// built from float4 loads, X re-laid out to A-frag via xch roundtrip.
// 4 waves x 16 rows per block, grid = NQ/64 = 256 blocks.
// ---------------------------------------------------------------------------
__global__ __launch_bounds__(256) void ft_kernel(const float* __restrict__ feat,
    const float* __restrict__ w1, const float* __restrict__ b1,
    const float* __restrict__ wq, const float* __restrict__ wk, const float* __restrict__ wv,
    float* __restrict__ qo, float* __restrict__ ko, float* __restrict__ vo) {
  __shared__ short W1b[512 * 8], Wqb[512 * 8], Wkb[512 * 8], Wvb[512 * 8];  // 32KB
  __shared__ float b1s[D];
  __shared__ short xch[4][16][72];    // per-wave bf16 X relayout buffer
  const int t = threadIdx.x;
  // ---- frag-pack the 4 weight matrices (pt's proven pack loop) ----
  for (int s = t; s < 512 * 4; s += 256) {
    const int m = s >> 9, rem = s & 511;
    const int tk = rem >> 6, l = rem & 63;
    const int tt = tk >> 1, ks = tk & 1;
    const float* src = (m == 0) ? w1 : ((m == 1) ? wq : ((m == 2) ? wk : wv));
    short* dst = (m == 0) ? W1b : ((m == 1) ? Wqb : ((m == 2) ? Wkb : Wvb));
#pragma unroll
    for (int j = 0; j < 8; ++j) {
      const int k = ((l >> 4) << 3) + j + (ks << 5);
      const int n = (l & 15) + (tt << 4);
      dst[rem * 8 + j] = f2bf(src[k * D + n]);
    }
  }
  if (t < 64) b1s[t] = b1[t];
  __syncthreads();

  const int w = t >> 6, lane = t & 63;
  const int l15 = lane & 15, g = lane >> 4;
  const int row0 = blockIdx.x * 64 + w * 16;

  // ---- feat tile -> A-frag (lane l: rows row0+l15, ch 8g+j+32ks) ----
  short8 fa[2];
#pragma unroll
  for (int ks = 0; ks < 2; ++ks) {
    const int c0 = g * 8 + ks * 32;
    const float4 f0 = *(const float4*)&feat[(size_t)(row0 + l15) * D + c0];
    const float4 f1 = *(const float4*)&feat[(size_t)(row0 + l15) * D + c0 + 4];
    fa[ks][0] = f2bf(f0.x); fa[ks][1] = f2bf(f0.y);
    fa[ks][2] = f2bf(f0.z); fa[ks][3] = f2bf(f0.w);
    fa[ks][4] = f2bf(f1.x); fa[ks][5] = f2bf(f1.y);
    fa[ks][6] = f2bf(f1.z); fa[ks][7] = f2bf(f1.w);
  }
  // ---- X = feat@w1 + b1 ----
#pragma unroll
  for (int tt = 0; tt < 4; ++tt) {
    f32x4 acc = {0.f, 0.f, 0.f, 0.f};
    acc = MFMA16(fa[0], *(const short8*)&W1b[((tt * 2 + 0) * 64 + lane) * 8], acc);
    acc = MFMA16(fa[1], *(const short8*)&W1b[((tt * 2 + 1) * 64 + lane) * 8], acc);
    const float bb = b1s[l15 + tt * 16];
#pragma unroll
    for (int r = 0; r < 4; ++r)
      xch[w][4 * g + r][l15 + 16 * tt] = f2bf(acc[r] + bb);
  }
  __syncthreads();  // xch(X) visible before cross-lane A-frag read
  const short8 xa0 = *(const short8*)&xch[w][l15][g * 8];
  const short8 xa1 = *(const short8*)&xch[w][l15][g * 8 + 32];

  // ---- Q = X@wq; K = X@wk; V = X@wv (D-frag scatter stores) ----
#pragma unroll
  for (int tt = 0; tt < 4; ++tt) {
    f32x4 acc = {0.f, 0.f, 0.f, 0.f};
    acc = MFMA16(xa0, *(const short8*)&Wqb[((tt * 2 + 0) * 64 + lane) * 8], acc);
    acc = MFMA16(xa1, *(const short8*)&Wqb[((tt * 2 + 1) * 64 + lane) * 8], acc);
#pragma unroll
    for (int r = 0; r < 4; ++r)
      qo[(size_t)(row0 + 4 * g + r) * D + l15 + 16 * tt] = acc[r];
  }
#pragma unroll
  for (int tt = 0; tt < 4; ++tt) {
    f32x4 acc = {0.f, 0.f, 0.f, 0.f};
    acc = MFMA16(xa0, *(const short8*)&Wkb[((tt * 2 + 0) * 64 + lane) * 8], acc);
    acc = MFMA16(xa1, *(const short8*)&Wkb[((tt * 2 + 1) * 64 + lane) * 8], acc);
#pragma unroll
    for (int r = 0; r < 4; ++r)
      ko[(size_t)(row0 + 4 * g + r) * D + l15 + 16 * tt] = acc[r];
  }
#pragma unroll
  for (int tt = 0; tt < 4; ++tt) {
    f32x4 acc = {0.f, 0.f, 0.f, 0.f};
    acc = MFMA16(xa0, *(const short8*)&Wvb[((tt * 2 + 0) * 64 + lane) * 8], acc);
    acc = MFMA16(xa1, *(const short8*)&Wvb[((tt * 2 + 1) * 64 + lane) * 8], acc);
#pragma unroll
    for (int r = 0; r < 4; ++r)
      vo[(size_t)(row0 + 4 * g + r) * D + l15 + 16 * tt] = acc[r];
  }
}

// ---------------------------------------------------------------------------
// Kernel 3: MFMA point-transformer core (round-11 verbatim).
// ---------------------------------------------------------------------------
__global__ __launch_bounds__(256, 4) void pt_kernel(const float* __restrict__ coords,
    const float* __restrict__ feat,
    const float* __restrict__ qws, const float* __restrict__ kws, const float* __restrict__ vws,
    const int* __restrict__ knn,
    const float* __restrict__ wp1, const float* __restrict__ bp1,
    const float* __restrict__ wp2, const float* __restrict__ bp2,
    const float* __restrict__ wm1, const float* __restrict__ bm1,
    const float* __restrict__ wm2, const float* __restrict__ bm2,
    const float* __restrict__ w2g, const float* __restrict__ b2,
    float* __restrict__ out, float* __restrict__ attn_g) {
  __shared__ short WBp[512 * 8], WBm1[512 * 8], WBm2[512 * 8];  // frag-packed weights
  __shared__ float wp1t[D * 4];       // (wp1_x, wp1_y, wp1_z, bp1) per channel
  __shared__ float biases[4 * D];     // bp2, bm1, bm2, b2
  __shared__ int knnq[4][PT_QPW][16];
  __shared__ short xch[4][16][72];    // per-wave bf16 exchange; 144B rows (16B-aligned)

  const int t = threadIdx.x;
  // ---- weight prep (frag order: dst[((tt*2+ks)*64 + lane)*8 + j] = W[k][n]) ----
  for (int s = t; s < 512 * 3; s += 256) {
    const int m = s >> 9, rem = s & 511;
    const int tk = rem >> 6, l = rem & 63;
    const int tt = tk >> 1, ks = tk & 1;
    const float* src = (m == 0) ? wp2 : ((m == 1) ? wm1 : wm2);
    short* dst = (m == 0) ? WBp : ((m == 1) ? WBm1 : WBm2);
#pragma unroll
    for (int j = 0; j < 8; ++j) {
      const int k = ((l >> 4) << 3) + j + (ks << 5);
      const int n = (l & 15) + (tt << 4);
      dst[rem * 8 + j] = f2bf(src[k * D + n]);
    }
  }
  if (t < 64) {
    wp1t[t * 4 + 0] = wp1[t];
    wp1t[t * 4 + 1] = wp1[D + t];
    wp1t[t * 4 + 2] = wp1[2 * D + t];
    wp1t[t * 4 + 3] = bp1[t];
    biases[t] = bp2[t]; biases[64 + t] = bm1[t];
    biases[128 + t] = bm2[t]; biases[192 + t] = b2[t];
  }
  const int w = t >> 6, lane = t & 63;
  const int qbase0 = blockIdx.x * (4 * PT_QPW) + w * PT_QPW;
  {
    const int q = lane >> 4, k = lane & 15;
    const int qi = qbase0 + q;
    const int bbase = (qi >> 12) << 12;
    knnq[w][q][k] = bbase + knn[(size_t)qi * 16 + k];
  }
  __syncthreads();

  const int l15 = lane & 15, g = lane >> 4;
  float ovq[PT_QPW];

  for (int q = 0; q < PT_QPW; ++q) {
    const int qi = qbase0 + q;
    const int gjA = knnq[w][q][l15];
    // ---- h1 = relu(rel @ wp1 + bp1), built directly in A-frag layout ----
    const float qx = coords[(size_t)qi * 3], qy = coords[(size_t)qi * 3 + 1], qz = coords[(size_t)qi * 3 + 2];
    const float rx = qx - coords[(size_t)gjA * 3];
    const float ry = qy - coords[(size_t)gjA * 3 + 1];
    const float rz = qz - coords[(size_t)gjA * 3 + 2];
    short8 ha[2];
#pragma unroll
    for (int ks = 0; ks < 2; ++ks) {
#pragma unroll
      for (int j = 0; j < 8; ++j) {
        const int c = g * 8 + j + ks * 32;
        const float4 wv = *(const float4*)&wp1t[c * 4];
        float h = fmaf(rx, wv.x, fmaf(ry, wv.y, fmaf(rz, wv.z, wv.w)));
        ha[ks][j] = f2bf(fmaxf(h, 0.f));
      }
    }
    // ---- pos_enc = h1 @ wp2 + bp2 (f32 in pe_d regs; bf16 copy to xch) ----
    f32x4 pe_d[4];
#pragma unroll
    for (int tt = 0; tt < 4; ++tt) {
      f32x4 acc = {0.f, 0.f, 0.f, 0.f};
      acc = MFMA16(ha[0], *(const short8*)&WBp[((tt * 2 + 0) * 64 + lane) * 8], acc);
      acc = MFMA16(ha[1], *(const short8*)&WBp[((tt * 2 + 1) * 64 + lane) * 8], acc);
      const float bb = biases[l15 + tt * 16];
#pragma unroll
      for (int r = 0; r < 4; ++r) {
        pe_d[tt][r] = acc[r] + bb;
        xch[w][4 * g + r][l15 + 16 * tt] = f2bf(pe_d[tt][r]);
      }
    }
    __syncthreads();  // xch(pe) visible before cross-lane A-frag build
    // ---- a = q - k_g + pos_enc, in A-frag layout ----
    short8 aa[2];
#pragma unroll
    for (int ks = 0; ks < 2; ++ks) {
      const int c0 = g * 8 + ks * 32;
      const float4 q0 = *(const float4*)&qws[(size_t)qi * D + c0];
      const float4 q1 = *(const float4*)&qws[(size_t)qi * D + c0 + 4];
      const float4 k0 = *(const float4*)&kws[(size_t)gjA * D + c0];
      const float4 k1 = *(const float4*)&kws[(size_t)gjA * D + c0 + 4];
      const short8 pv = *(const short8*)&xch[w][l15][c0];
      aa[ks][0] = f2bf(q0.x - k0.x + bf2f(pv[0]));
      aa[ks][1] = f2bf(q0.y - k0.y + bf2f(pv[1]));
      aa[ks][2] = f2bf(q0.z - k0.z + bf2f(pv[2]));
      aa[ks][3] = f2bf(q0.w - k0.w + bf2f(pv[3]));
      aa[ks][4] = f2bf(q1.x - k1.x + bf2f(pv[4]));
      aa[ks][5] = f2bf(q1.y - k1.y + bf2f(pv[5]));
      aa[ks][6] = f2bf(q1.z - k1.z + bf2f(pv[6]));
      aa[ks][7] = f2bf(q1.w - k1.w + bf2f(pv[7]));
    }
    // ---- a2 = relu(a @ wm1 + bm1) -> bf16 -> xch (reuse; pe dead now) ----
#pragma unroll
    for (int tt = 0; tt < 4; ++tt) {
      f32x4 acc = {0.f, 0.f, 0.f, 0.f};
      acc = MFMA16(aa[0], *(const short8*)&WBm1[((tt * 2 + 0) * 64 + lane) * 8], acc);
      acc = MFMA16(aa[1], *(const short8*)&WBm1[((tt * 2 + 1) * 64 + lane) * 8], acc);
      const float bb = biases[64 + l15 + tt * 16];
#pragma unroll
      for (int r = 0; r < 4; ++r)
        xch[w][4 * g + r][l15 + 16 * tt] = f2bf(fmaxf(acc[r] + bb, 0.f));
    }
    __syncthreads();  // xch(a2) visible before cross-lane reads
    // ---- a3 = a2 @ wm2 + bm2 ----
    const short8 a20 = *(const short8*)&xch[w][l15][g * 8];
    const short8 a21 = *(const short8*)&xch[w][l15][g * 8 + 32];
    f32x4 s3[4];
#pragma unroll
    for (int tt = 0; tt < 4; ++tt) {
      f32x4 acc = {0.f, 0.f, 0.f, 0.f};
      acc = MFMA16(a20, *(const short8*)&WBm2[((tt * 2 + 0) * 64 + lane) * 8], acc);
      acc = MFMA16(a21, *(const short8*)&WBm2[((tt * 2 + 1) * 64 + lane) * 8], acc);
      const float bb = biases[128 + l15 + tt * 16];
#pragma unroll
      for (int r = 0; r < 4; ++r) s3[tt][r] = acc[r] + bb;
    }
    // ---- softmax over the 16 neighbors (rows), per channel (col) ----
    float att[4][4];
#pragma unroll
    for (int tt = 0; tt < 4; ++tt) {
      float v0 = s3[tt][0] * 0.125f, v1 = s3[tt][1] * 0.125f;
      float v2 = s3[tt][2] * 0.125f, v3 = s3[tt][3] * 0.125f;
      float mx = fmaxf(fmaxf(v0, v1), fmaxf(v2, v3));
      mx = fmaxf(mx, __shfl_xor(mx, 16));
      mx = fmaxf(mx, __shfl_xor(mx, 32));
      float e0 = __expf(v0 - mx), e1 = __expf(v1 - mx), e2 = __expf(v2 - mx), e3 = __expf(v3 - mx);
      float sm = (e0 + e1) + (e2 + e3);
      sm += __shfl_xor(sm, 16);
      sm += __shfl_xor(sm, 32);
      const float inv = 1.0f / sm;
      att[tt][0] = e0 * inv; att[tt][1] = e1 * inv;
      att[tt][2] = e2 * inv; att[tt][3] = e3 * inv;
    }
    // ---- attn store: bf16 bounce via xch -> 4x 1KB coalesced stores ----
    __syncthreads();  // xch(a2) reads complete in all lanes
#pragma unroll
    for (int tt = 0; tt < 4; ++tt)
#pragma unroll
      for (int r = 0; r < 4; ++r)
        xch[w][4 * g + r][l15 + 16 * tt] = f2bf(att[tt][r]);
    __syncthreads();  // xch(attn) visible
    {
      float* aq = attn_g + (size_t)qi * KNBR * D;
#pragma unroll
      for (int k = 0; k < 4; ++k) {
        const short4v sv = *(const short4v*)&xch[w][g + 4 * k][4 * l15];
        float4 fv;
        fv.x = bf2f(sv.x); fv.y = bf2f(sv.y); fv.z = bf2f(sv.z); fv.w = bf2f(sv.w);
        *(float4*)(aq + lane * 4 + k * 256) = fv;
      }
    }
    // ---- out_vec = sum_k attn * (v_g + pos_enc); pe is register-local ----
    float ovp[4] = {0.f, 0.f, 0.f, 0.f};
#pragma unroll
    for (int r = 0; r < 4; ++r) {
      const int gjr = knnq[w][q][4 * g + r];
#pragma unroll
      for (int tt = 0; tt < 4; ++tt) {
        const float vv = vws[(size_t)gjr * D + l15 + 16 * tt];
        ovp[tt] = fmaf(att[tt][r], vv + pe_d[tt][r], ovp[tt]);
      }
    }
#pragma unroll
    for (int tt = 0; tt < 4; ++tt) {
      ovp[tt] += __shfl_xor(ovp[tt], 16);
      ovp[tt] += __shfl_xor(ovp[tt], 32);
    }
    ovq[q] = (g == 0) ? ovp[0] : ((g == 1) ? ovp[1] : ((g == 2) ? ovp[2] : ovp[3]));
  }

  // ---- out = ov @ w2 + b2 + feat, 4 queries interleaved (ILP), w2 from L1 ----
  float o2[PT_QPW];
#pragma unroll
  for (int q = 0; q < PT_QPW; ++q) o2[q] = biases[192 + lane];
#pragma unroll 8
  for (int i = 0; i < D; ++i) {
    const float wv = w2g[i * D + lane];
#pragma unroll
    for (int q = 0; q < PT_QPW; ++q) o2[q] = fmaf(rl(ovq[q], i), wv, o2[q]);
  }
#pragma unroll
  for (int q = 0; q < PT_QPW; ++q) {
    const int qi = qbase0 + q;
    out[(size_t)qi * D + lane] = o2[q] + feat[(size_t)qi * D + lane];
  }
}

// ---------------------------------------------------------------------------
extern "C" void kernel_launch(void* const* d_in, const int* in_sizes, int n_in,
                              void* d_out, int out_size, void* d_ws, size_t ws_size,
                              hipStream_t stream) {
  const float* coords = (const float*)d_in[0];
  const float* feat   = (const float*)d_in[1];
  const float* w1  = (const float*)d_in[2];
  const float* b1  = (const float*)d_in[3];
  const float* w2  = (const float*)d_in[4];
  const float* b2  = (const float*)d_in[5];
  const float* wq  = (const float*)d_in[6];
  const float* wk  = (const float*)d_in[7];
  const float* wv  = (const float*)d_in[8];
  const float* wm1 = (const float*)d_in[9];
  const float* bm1 = (const float*)d_in[10];
  const float* wm2 = (const float*)d_in[11];
  const float* bm2 = (const float*)d_in[12];
  const float* wp1 = (const float*)d_in[13];
  const float* bp1 = (const float*)d_in[14];
  const float* wp2 = (const float*)d_in[15];
  const float* bp2 = (const float*)d_in[16];

  // ws layout (disjoint): knn@0 (1MB), qws@1MB, kws@5MB, vws@9MB..13MB.
  int* knn = (int*)d_ws;
  float* qws = (float*)((char*)d_ws + (size_t)1 * (1 << 20));
  float* kws = (float*)((char*)d_ws + (size_t)5 * (1 << 20));
  float* vws = (float*)((char*)d_ws + (size_t)9 * (1 << 20));
  float* out  = (float*)d_out;
  float* attn = out + (size_t)NQ * D;

  hipLaunchKernelGGL(knn_kernel, dim3(NQ / (4 * QPW)), dim3(256), 0, stream,
                     coords, knn);
  hipLaunchKernelGGL(ft_kernel, dim3(NQ / 64), dim3(256), 0, stream,
                     feat, w1, b1, wq, wk, wv, qws, kws, vws);
  hipLaunchKernelGGL(pt_kernel, dim3(NQ / (4 * PT_QPW)), dim3(256), 0, stream,
                     coords, feat, qws, kws, vws, knn,
                     wp1, bp1, wp2, bp2, wm1, bm1, wm2, bm2, w2, b2, out, attn);
}